// Round 1
// baseline (1798.477 us; speedup 1.0000x reference)
//
#include <hip/hip_runtime.h>
#include <math.h>

#define SEQ 2048
#define BSZ 2
#define DM 512
#define DIN 1024
#define DSTATE 16
#define NH 16
#define HD 64
#define CONVDIM 1056
#define DINPROJ 2096
#define DFF 2048
#define ROWS (BSZ*SEQ)

__device__ __forceinline__ float sigf(float x){ return 1.f/(1.f+expf(-x)); }

__device__ __forceinline__ float wave_reduce(float v){
#pragma unroll
  for (int o = 32; o > 0; o >>= 1) v += __shfl_down(v, o);
  return v;
}

// 256-thread block reduce (4 waves)
__device__ __forceinline__ float block_reduce_256(float v, float* sbuf){
  v = wave_reduce(v);
  int lane = threadIdx.x & 63, wid = threadIdx.x >> 6;
  if (lane == 0) sbuf[wid] = v;
  __syncthreads();
  float s = sbuf[0] + sbuf[1] + sbuf[2] + sbuf[3];
  __syncthreads();
  return s;
}

// ---------------- rmsnorm over D=512 ----------------
__global__ __launch_bounds__(256)
void rmsnorm512_k(const float* __restrict__ x, const float* __restrict__ w,
                  float* __restrict__ y, float eps){
  __shared__ float sbuf[4];
  int r = blockIdx.x;
  const float* xr = x + (size_t)r*DM;
  float* yr = y + (size_t)r*DM;
  float v0 = xr[threadIdx.x];
  float v1 = xr[threadIdx.x + 256];
  float ss = block_reduce_256(v0*v0 + v1*v1, sbuf);
  float rs = rsqrtf(ss*(1.f/DM) + eps);
  yr[threadIdx.x]       = w[threadIdx.x]*v0*rs;
  yr[threadIdx.x + 256] = w[threadIdx.x+256]*v1*rs;
}

// ---------------- gated fusion (modifies query rows in place) ----------------
__global__ __launch_bounds__(256)
void gated_fusion_k(float* __restrict__ h,
                    const float* __restrict__ wfc_w, const float* __restrict__ wfc_b,
                    const float* __restrict__ gfc_w, const float* __restrict__ gfc_b){
  int c = blockIdx.x;                // 0..B*NCK-1, contiguous chunks of 16 rows
  float* base = h + (size_t)c*16*DM;
  float* qrow = base + 15*DM;
  __shared__ float q[DM];
  __shared__ float dots[16];
  for (int i = threadIdx.x; i < DM; i += 256) q[i] = qrow[i];
  __syncthreads();
  int wid = threadIdx.x >> 6, lane = threadIdx.x & 63;
  for (int f = wid; f < 16; f += 4){
    const float* wf = (f < 15) ? (wfc_w + (size_t)f*DM) : gfc_w;
    float s = 0.f;
    for (int i = lane; i < DM; i += 64) s += q[i]*wf[i];
    s = wave_reduce(s);
    if (lane == 0) dots[f] = s;
  }
  __syncthreads();
  if (threadIdx.x == 0){
    float mx = -1e30f;
    for (int f = 0; f < 15; f++){ dots[f] += wfc_b[f]; mx = fmaxf(mx, dots[f]); }
    float sum = 0.f;
    for (int f = 0; f < 15; f++){ float e = expf(dots[f]-mx); dots[f] = e; sum += e; }
    float inv = 1.f/sum;
    for (int f = 0; f < 15; f++) dots[f] *= inv;
    float g = sigf(dots[15] + gfc_b[0]);
    dots[15] = g*0.98f + 0.01f;
  }
  __syncthreads();
  float gate = dots[15];
  for (int d = threadIdx.x; d < DM; d += 256){
    float agg = 0.f;
#pragma unroll
    for (int f = 0; f < 15; f++) agg += base[(size_t)f*DM + d]*dots[f];
    qrow[d] = q[d]*(1.f-gate) + agg*gate;
  }
}

// ---------------- generic C = A @ W^T, optional bias/silu/epilogue adds/flip ----------------
// A: (M,K) row-major (row flipped within each SEQ batch if flip)
// W: (N,K) row-major; C: (M,N)
__global__ __launch_bounds__(256)
void gemm_k(const float* __restrict__ A, const float* __restrict__ W,
            const float* __restrict__ bias,
            const float* __restrict__ add1, const float* __restrict__ add2,
            float* __restrict__ C, int M, int N, int K, int flip, int act){
  __shared__ __align__(16) float As[16][68];
  __shared__ __align__(16) float Bs[16][68];
  int tid = threadIdx.x;
  int n0 = blockIdx.x*64, m0 = blockIdx.y*64;
  int lr = tid >> 2, lk = (tid & 3)*4;
  int tx = tid & 15, ty = tid >> 4;
  float acc[4][4] = {};
  int am = m0 + lr;
  if (flip) am = (am & ~(SEQ-1)) | ((SEQ-1) - (am & (SEQ-1)));
  const float* Arow = A + (size_t)am*K + lk;
  const float* Wrow = (n0 + lr < N) ? (W + (size_t)(n0+lr)*K + lk) : nullptr;
  for (int k0 = 0; k0 < K; k0 += 16){
    float4 av = *(const float4*)(Arow + k0);
    float4 wv = Wrow ? *(const float4*)(Wrow + k0) : make_float4(0.f,0.f,0.f,0.f);
    As[lk+0][lr]=av.x; As[lk+1][lr]=av.y; As[lk+2][lr]=av.z; As[lk+3][lr]=av.w;
    Bs[lk+0][lr]=wv.x; Bs[lk+1][lr]=wv.y; Bs[lk+2][lr]=wv.z; Bs[lk+3][lr]=wv.w;
    __syncthreads();
#pragma unroll
    for (int k = 0; k < 16; k++){
      float4 a = *(const float4*)&As[k][ty*4];
      float4 b = *(const float4*)&Bs[k][tx*4];
      acc[0][0] += a.x*b.x; acc[0][1] += a.x*b.y; acc[0][2] += a.x*b.z; acc[0][3] += a.x*b.w;
      acc[1][0] += a.y*b.x; acc[1][1] += a.y*b.y; acc[1][2] += a.y*b.z; acc[1][3] += a.y*b.w;
      acc[2][0] += a.z*b.x; acc[2][1] += a.z*b.y; acc[2][2] += a.z*b.z; acc[2][3] += a.z*b.w;
      acc[3][0] += a.w*b.x; acc[3][1] += a.w*b.y; acc[3][2] += a.w*b.z; acc[3][3] += a.w*b.w;
    }
    __syncthreads();
  }
#pragma unroll
  for (int i = 0; i < 4; i++){
    int m = m0 + ty*4 + i;
    float* crow = C + (size_t)m*N;
#pragma unroll
    for (int j = 0; j < 4; j++){
      int n = n0 + tx*4 + j;
      if (n < N){
        float v = acc[i][j];
        if (bias) v += bias[n];
        if (act == 1) v = v*sigf(v);
        if (add1) v += add1[(size_t)m*N + n] + add2[(size_t)m*N + n];
        crow[n] = v;
      }
    }
  }
}

// ---------------- causal depthwise conv (width 4) + silu + split ----------------
__global__ __launch_bounds__(256)
void conv_silu_k(const float* __restrict__ zx, const float* __restrict__ convw,
                 const float* __restrict__ convb,
                 float* __restrict__ xs, float* __restrict__ Bm, float* __restrict__ Cm){
  int c = blockIdx.x*256 + threadIdx.x;
  int r = blockIdx.y;
  if (c >= CONVDIM) return;
  int l = r & (SEQ-1);
  int rbase = r - l;
  float acc = convb[c];
#pragma unroll
  for (int k = 0; k < 4; k++){
    int ls = l + k - 3;
    if (ls >= 0) acc += zx[(size_t)(rbase+ls)*DINPROJ + DIN + c]*convw[c*4 + k];
  }
  float v = acc*sigf(acc);
  if (c < DIN) xs[(size_t)r*DIN + c] = v;
  else if (c < DIN + DSTATE) Bm[(size_t)r*DSTATE + (c - DIN)] = v;
  else Cm[(size_t)r*DSTATE + (c - DIN - DSTATE)] = v;
}

// ---------------- dt: softplus + dA ----------------
__global__ __launch_bounds__(256)
void dt_k(const float* __restrict__ zx, const float* __restrict__ dtbias,
          const float* __restrict__ Alog, float* __restrict__ dtv, float* __restrict__ dAv){
  int idx = blockIdx.x*256 + threadIdx.x;
  if (idx >= ROWS*NH) return;
  int r = idx >> 4, hh = idx & 15;
  float x = zx[(size_t)r*DINPROJ + (DIN + CONVDIM) + hh] + dtbias[hh];
  float sp = (x > 20.f) ? x : log1pf(expf(x));
  dtv[idx] = sp;
  dAv[idx] = expf(-expf(Alog[hh])*sp);
}

// ---------------- sequential selective scan: one block per (b,h) ----------------
__global__ __launch_bounds__(1024)
void scan_k(const float* __restrict__ xs, const float* __restrict__ Bm,
            const float* __restrict__ Cm, const float* __restrict__ dtv,
            const float* __restrict__ dAv, float* __restrict__ y){
  int b = blockIdx.x >> 4, h = blockIdx.x & 15;
  int p = threadIdx.x >> 4, n = threadIdx.x & 15;
  __shared__ float sx[64][64];
  __shared__ float sBdt[64][16];
  __shared__ float sC[64][16];
  __shared__ float sdA[64];
  const float* xb  = xs  + (size_t)b*SEQ*DIN + h*HD;
  const float* Bb  = Bm  + (size_t)b*SEQ*DSTATE;
  const float* Cb  = Cm  + (size_t)b*SEQ*DSTATE;
  const float* dtb = dtv + (size_t)b*SEQ*NH + h;
  const float* dAb = dAv + (size_t)b*SEQ*NH + h;
  float* yb = y + (size_t)b*SEQ*DIN + h*HD;
  float hst = 0.f;
  for (int l0 = 0; l0 < SEQ; l0 += 64){
    __syncthreads();
    for (int i = threadIdx.x; i < 64*64; i += 1024){
      int t = i >> 6, pp = i & 63;
      sx[t][pp] = xb[(size_t)(l0+t)*DIN + pp];
    }
    if (threadIdx.x < 64) sdA[threadIdx.x] = dAb[(size_t)(l0+threadIdx.x)*NH];
    for (int i = threadIdx.x; i < 64*16; i += 1024){
      int t = i >> 4, nn = i & 15;
      float dt_t = dtb[(size_t)(l0+t)*NH];
      sBdt[t][nn] = Bb[(size_t)(l0+t)*DSTATE + nn]*dt_t;
      sC[t][nn]   = Cb[(size_t)(l0+t)*DSTATE + nn];
    }
    __syncthreads();
#pragma unroll 4
    for (int t = 0; t < 64; t++){
      hst = fmaf(sdA[t], hst, sBdt[t][n]*sx[t][p]);
      float v = hst*sC[t][n];
      v += __shfl_xor(v, 1); v += __shfl_xor(v, 2);
      v += __shfl_xor(v, 4); v += __shfl_xor(v, 8);
      if (n == 0) yb[(size_t)(l0+t)*DIN + p] = v;
    }
  }
}

// ---------------- y = (yscan + D*x) * silu(z); rmsnorm(1024); in-place on yscan ----------------
__global__ __launch_bounds__(256)
void gated_rms_k(float* __restrict__ y, const float* __restrict__ xs,
                 const float* __restrict__ zx, const float* __restrict__ Dp,
                 const float* __restrict__ normw){
  __shared__ float sbuf[4];
  int r = blockIdx.x;
  float* yr = y + (size_t)r*DIN;
  const float* xr = xs + (size_t)r*DIN;
  const float* zr = zx + (size_t)r*DINPROJ;
  float vals[4]; float ss = 0.f;
#pragma unroll
  for (int i = 0; i < 4; i++){
    int d = threadIdx.x + i*256;
    float yv = yr[d] + Dp[d >> 6]*xr[d];
    float z = zr[d];
    float g = yv*(z*sigf(z));
    vals[i] = g; ss += g*g;
  }
  ss = block_reduce_256(ss, sbuf);
  float rs = rsqrtf(ss*(1.f/DIN) + 1e-5f);
#pragma unroll
  for (int i = 0; i < 4; i++){
    int d = threadIdx.x + i*256;
    yr[d] = normw[d]*vals[i]*rs;
  }
}

// ---------------- hsum = outf + flip(outb) + hid; h2 = rmsnorm(hsum, norm2_w) ----------------
__global__ __launch_bounds__(256)
void addres_rms_k(const float* __restrict__ outf, const float* __restrict__ outb,
                  const float* __restrict__ hid, const float* __restrict__ w,
                  float* __restrict__ hsum, float* __restrict__ h2){
  __shared__ float sbuf[4];
  int r = blockIdx.x;
  int l = r & (SEQ-1);
  int rb = (r - l) + ((SEQ-1) - l);
  float vals[2]; float ss = 0.f;
#pragma unroll
  for (int i = 0; i < 2; i++){
    int d = threadIdx.x + i*256;
    float v = outf[(size_t)r*DM + d] + outb[(size_t)rb*DM + d] + hid[(size_t)r*DM + d];
    hsum[(size_t)r*DM + d] = v;
    vals[i] = v; ss += v*v;
  }
  ss = block_reduce_256(ss, sbuf);
  float rs = rsqrtf(ss*(1.f/DM) + 1e-6f);
#pragma unroll
  for (int i = 0; i < 2; i++){
    int d = threadIdx.x + i*256;
    h2[(size_t)r*DM + d] = w[d]*vals[i]*rs;
  }
}

extern "C" void kernel_launch(void* const* d_in, const int* in_sizes, int n_in,
                              void* d_out, int out_size, void* d_ws, size_t ws_size,
                              hipStream_t stream){
  const float* hid     = (const float*)d_in[0];
  const float* norm1_w = (const float*)d_in[1];
  const float* wfc_w   = (const float*)d_in[2];
  const float* wfc_b   = (const float*)d_in[3];
  const float* gfc_w   = (const float*)d_in[4];
  const float* gfc_b   = (const float*)d_in[5];
  const float* norm2_w = (const float*)d_in[6];
  const float* fc1_w   = (const float*)d_in[7];
  const float* fc1_b   = (const float*)d_in[8];
  const float* fc2_w   = (const float*)d_in[9];
  const float* fc2_b   = (const float*)d_in[10];
  const float* inproj[2]  = {(const float*)d_in[11], (const float*)d_in[19]};
  const float* convw[2]   = {(const float*)d_in[12], (const float*)d_in[20]};
  const float* convb[2]   = {(const float*)d_in[13], (const float*)d_in[21]};
  const float* dtbias[2]  = {(const float*)d_in[14], (const float*)d_in[22]};
  const float* Alog[2]    = {(const float*)d_in[15], (const float*)d_in[23]};
  const float* Dp[2]      = {(const float*)d_in[16], (const float*)d_in[24]};
  const float* normw[2]   = {(const float*)d_in[17], (const float*)d_in[25]};
  const float* outproj[2] = {(const float*)d_in[18], (const float*)d_in[26]};

  float* ws = (float*)d_ws;
  float* hnorm = ws;                       // 2,097,152
  float* zx    = hnorm + 2097152;          // 8,585,216 (reused later as a1)
  float* xs    = zx + 8585216;             // 4,194,304 (reused later as h2)
  float* Bmb   = xs + 4194304;             // 65,536
  float* Cmb   = Bmb + 65536;              // 65,536
  float* dtv   = Cmb + 65536;              // 65,536
  float* dAv   = dtv + 65536;              // 65,536
  float* ysc   = dAv + 65536;              // 4,194,304
  float* outd0 = ysc + 4194304;            // 2,097,152
  float* outd1 = outd0 + 2097152;          // 2,097,152
  float* hsum  = outd1 + 2097152;          // 2,097,152
  float* a1 = zx;
  float* h2 = xs;
  size_t need_bytes = (size_t)(25624576)*4;
  if (ws_size < need_bytes) return;  // not enough scratch; bail (bench will show mismatch)

  rmsnorm512_k<<<ROWS, 256, 0, stream>>>(hid, norm1_w, hnorm, 1e-6f);
  gated_fusion_k<<<BSZ*(SEQ/16), 256, 0, stream>>>(hnorm, wfc_w, wfc_b, gfc_w, gfc_b);

  float* outd[2] = {outd0, outd1};
  for (int dir = 0; dir < 2; dir++){
    gemm_k<<<dim3((DINPROJ+63)/64, ROWS/64), 256, 0, stream>>>(
        hnorm, inproj[dir], nullptr, nullptr, nullptr, zx, ROWS, DINPROJ, DM, dir, 0);
    conv_silu_k<<<dim3((CONVDIM+255)/256, ROWS), 256, 0, stream>>>(
        zx, convw[dir], convb[dir], xs, Bmb, Cmb);
    dt_k<<<(ROWS*NH+255)/256, 256, 0, stream>>>(zx, dtbias[dir], Alog[dir], dtv, dAv);
    scan_k<<<BSZ*NH, 1024, 0, stream>>>(xs, Bmb, Cmb, dtv, dAv, ysc);
    gated_rms_k<<<ROWS, 256, 0, stream>>>(ysc, xs, zx, Dp[dir], normw[dir]);
    gemm_k<<<dim3(DM/64, ROWS/64), 256, 0, stream>>>(
        ysc, outproj[dir], nullptr, nullptr, nullptr, outd[dir], ROWS, DM, DIN, 0, 0);
  }

  addres_rms_k<<<ROWS, 256, 0, stream>>>(outd0, outd1, hid, norm2_w, hsum, h2);
  gemm_k<<<dim3(DFF/64, ROWS/64), 256, 0, stream>>>(
      h2, fc1_w, fc1_b, nullptr, nullptr, a1, ROWS, DFF, DM, 0, 1);
  gemm_k<<<dim3(DM/64, ROWS/64), 256, 0, stream>>>(
      a1, fc2_w, fc2_b, hsum, hid, (float*)d_out, ROWS, DM, DFF, 0, 0);
}